// Round 14
// baseline (38.016 us; speedup 1.0000x reference)
//
#include <hip/hip_runtime.h>
#include <math.h>

// MAM "FullyConnected": C[n,m] = max_k(x[n,k]*w[m,k]) + min_k(...) + bias[m]
// plus argmax/argmin (first occurrence). N=1024, M=512, K=512, f32.
// d_out (read back as f32): C | argmax | argmin, each N*M.
//
// Round 14: R9/R13 were latency-bound (2 blocks/CU, 2.3 waves/SIMD, ~50%
// idle). 16x16 tiles -> 2048 blocks = 8 blocks/CU. 256-thr blocks: 64 base
// threads x 2x2 cells, k-split x4 (quarter == wave). w in LDS [16][132]
// (8.45KB, conflict-free: rows c*132 mod 32 cover all banks), x from
// global/L1 (TA pipe). R12's 4-way merge; recovery 1 cell/thread.

constexpr int NTOT = 1024;
constexpr int MTOT = 512;
constexpr int KTOT = 512;
constexpr int BN = 16;
constexpr int BM = 16;
constexpr int BK = 128;
constexpr int G  = 16;        // tournament group size
constexpr int LDSP = 132;     // rows 16B-aligned

__device__ __forceinline__ float max3f(float a, float b, float c) {
  float d; asm("v_max3_f32 %0, %1, %2, %3" : "=v"(d) : "v"(a), "v"(b), "v"(c)); return d;
}
__device__ __forceinline__ float min3f(float a, float b, float c) {
  float d; asm("v_min3_f32 %0, %1, %2, %3" : "=v"(d) : "v"(a), "v"(b), "v"(c)); return d;
}
__device__ __forceinline__ float fmul0(float a, float b) {  // a*b on the 2-cy FMA pipe
  float d; asm("v_fma_f32 %0, %1, %2, 0" : "=v"(d) : "v"(a), "v"(b)); return d;
}
__device__ __forceinline__ float4 f4mul(float4 a, float4 b) {
  return make_float4(fmul0(a.x, b.x), fmul0(a.y, b.y), fmul0(a.z, b.z), fmul0(a.w, b.w));
}

__device__ __forceinline__ void tree16(const float4& q0, const float4& q1,
                                       const float4& q2, const float4& q3,
                                       float& M, float& m) {
  M = fmaxf(max3f(max3f(q0.x, q0.y, q0.z), max3f(q0.w, q1.x, q1.y),
                  max3f(q1.z, q1.w, q2.x)),
            max3f(max3f(q2.y, q2.z, q2.w), q3.x, max3f(q3.y, q3.z, q3.w)));
  m = fminf(min3f(min3f(q0.x, q0.y, q0.z), min3f(q0.w, q1.x, q1.y),
                  min3f(q1.z, q1.w, q2.x)),
            min3f(min3f(q2.y, q2.z, q2.w), q3.x, min3f(q3.y, q3.z, q3.w)));
}

// value tree over one 16-k group for one cell + running group update.
// strict > / < : first group attaining the extremum wins (first occurrence).
#define CELL(S, A0, A1, A2, A3, B0, B1, B2, B3)                              \
  {                                                                          \
    const float4 q0 = f4mul(A0, B0), q1 = f4mul(A1, B1);                     \
    const float4 q2 = f4mul(A2, B2), q3 = f4mul(A3, B3);                     \
    float M, m;                                                              \
    tree16(q0, q1, q2, q3, M, m);                                            \
    const bool u = M > vmax##S;                                              \
    vmax##S = u ? M : vmax##S;  gx##S = u ? gk : gx##S;                      \
    const bool v = m < vmin##S;                                              \
    vmin##S = v ? m : vmin##S;  gn##S = v ? gk : gn##S;                      \
  }

// first k in [base, base+16) with x[k]*w[k] == tgt (descending selects ->
// first occurrence wins; +-0 compare-equal so fma(+0) targets match mul).
__device__ __forceinline__ int find_first_eq(const float* __restrict__ xr,
                                             const float* __restrict__ wr,
                                             float tgt, int base) {
  const float4 a0 = *(const float4*)(xr + 0),  a1 = *(const float4*)(xr + 4);
  const float4 a2 = *(const float4*)(xr + 8),  a3 = *(const float4*)(xr + 12);
  const float4 b0 = *(const float4*)(wr + 0),  b1 = *(const float4*)(wr + 4);
  const float4 b2 = *(const float4*)(wr + 8),  b3 = *(const float4*)(wr + 12);
  int idx = base;
  idx = (a3.w * b3.w == tgt) ? base + 15 : idx;
  idx = (a3.z * b3.z == tgt) ? base + 14 : idx;
  idx = (a3.y * b3.y == tgt) ? base + 13 : idx;
  idx = (a3.x * b3.x == tgt) ? base + 12 : idx;
  idx = (a2.w * b2.w == tgt) ? base + 11 : idx;
  idx = (a2.z * b2.z == tgt) ? base + 10 : idx;
  idx = (a2.y * b2.y == tgt) ? base +  9 : idx;
  idx = (a2.x * b2.x == tgt) ? base +  8 : idx;
  idx = (a1.w * b1.w == tgt) ? base +  7 : idx;
  idx = (a1.z * b1.z == tgt) ? base +  6 : idx;
  idx = (a1.y * b1.y == tgt) ? base +  5 : idx;
  idx = (a1.x * b1.x == tgt) ? base +  4 : idx;
  idx = (a0.w * b0.w == tgt) ? base +  3 : idx;
  idx = (a0.z * b0.z == tgt) ? base +  2 : idx;
  idx = (a0.y * b0.y == tgt) ? base +  1 : idx;
  idx = (a0.x * b0.x == tgt) ? base +  0 : idx;
  return idx;
}

__global__ __launch_bounds__(256, 4) void mam_kernel(
    const float* __restrict__ X,   // [NTOT][KTOT]
    const float* __restrict__ W,   // [MTOT][KTOT]
    const float* __restrict__ B,   // [MTOT]
    float* __restrict__ out)
{
  __shared__ float sw[BM][LDSP];   // 8.45 KB (w tile only; x bypasses LDS)

  const int th      = threadIdx.x;     // 0..255
  const int quarter = th >> 6;         // == wave id; k-split quarter
  const int t       = th & 63;
  const int n0 = blockIdx.y * BN;
  const int m0 = blockIdx.x * BM;

  const int tn = t >> 3;               // 0..7
  const int tm = t & 7;                // 0..7
  const int r0 = tn, r1 = tn + 8;      // 2 output rows (of 16)
  const int c0 = tm, c1 = tm + 8;      // 2 output cols (of 16)
  const int kbase = quarter * 32;      // this quarter's kk range within BK

  const float* Xr0 = &X[(n0 + r0) * KTOT];
  const float* Xr1 = &X[(n0 + r1) * KTOT];

  float vmax00 = -INFINITY, vmax01 = -INFINITY, vmax10 = -INFINITY, vmax11 = -INFINITY;
  float vmin00 =  INFINITY, vmin01 =  INFINITY, vmin10 =  INFINITY, vmin11 =  INFINITY;
  int   gx00 = 0, gx01 = 0, gx10 = 0, gx11 = 0;
  int   gn00 = 0, gn01 = 0, gn10 = 0, gn11 = 0;

  #pragma unroll 1
  for (int kc = 0; kc < KTOT; kc += BK) {
    __syncthreads();  // protect LDS from previous iteration's readers
    // stage w[16][128]: 512 float4, 256 threads -> 2 each
    #pragma unroll
    for (int j = 0; j < 2; ++j) {
      const int id = th + 256 * j;     // 0..511
      const int r  = id >> 5;          // 0..15
      const int f  = id & 31;
      *reinterpret_cast<float4*>(&sw[r][f * 4]) =
          *reinterpret_cast<const float4*>(&W[(m0 + r) * KTOT + kc + f * 4]);
    }
    __syncthreads();

    #pragma unroll
    for (int g = 0; g < 2; ++g) {      // this quarter's 2 groups of 16 k
      const int off = kbase + g * G;   // wave-uniform
      const int gk  = kc + off;
      // x straight from global (L1/L2-resident, broadcast across 8 lanes/row)
      const float4 xa0 = *reinterpret_cast<const float4*>(Xr0 + gk + 0);
      const float4 xa1 = *reinterpret_cast<const float4*>(Xr0 + gk + 4);
      const float4 xa2 = *reinterpret_cast<const float4*>(Xr0 + gk + 8);
      const float4 xa3 = *reinterpret_cast<const float4*>(Xr0 + gk + 12);
      const float4 xb0 = *reinterpret_cast<const float4*>(Xr1 + gk + 0);
      const float4 xb1 = *reinterpret_cast<const float4*>(Xr1 + gk + 4);
      const float4 xb2 = *reinterpret_cast<const float4*>(Xr1 + gk + 8);
      const float4 xb3 = *reinterpret_cast<const float4*>(Xr1 + gk + 12);
      // w from LDS (rows c*132 mod 32 cover all 32 banks -> conflict-free)
      const float4* wap = reinterpret_cast<const float4*>(&sw[c0][off]);
      const float4* wbp = reinterpret_cast<const float4*>(&sw[c1][off]);
      const float4 wa0 = wap[0], wa1 = wap[1], wa2 = wap[2], wa3 = wap[3];
      const float4 wb0 = wbp[0], wb1 = wbp[1], wb2 = wbp[2], wb3 = wbp[3];

      CELL(00, xa0, xa1, xa2, xa3, wa0, wa1, wa2, wa3)
      CELL(01, xa0, xa1, xa2, xa3, wb0, wb1, wb2, wb3)
      CELL(10, xb0, xb1, xb2, xb3, wa0, wa1, wa2, wa3)
      CELL(11, xb0, xb1, xb2, xb3, wb0, wb1, wb2, wb3)
    }
  }

  // ---- cross-quarter merge through LDS (ties -> min group id) ----
  // 256 cells (16x16) * float4 = 4 KB per partial buffer; both fit in sw.
  __syncthreads();
  float* combA = &sw[0][0];
  float* combB = &sw[0][0] + 1024;

#define WRITE_ONE(S, RR, CC, comb)                                           \
  *reinterpret_cast<float4*>(&(comb)[((RR) * 16 + (CC)) * 4]) =              \
      make_float4(vmax##S, __int_as_float(gx##S), vmin##S, __int_as_float(gn##S));

#define WRITE_PART(comb)                                                     \
  {                                                                          \
    WRITE_ONE(00, r0, c0, comb) WRITE_ONE(01, r0, c1, comb)                  \
    WRITE_ONE(10, r1, c0, comb) WRITE_ONE(11, r1, c1, comb)                  \
  }

#define MERGE_ONE(S, RR, CC, comb)                                           \
  {                                                                          \
    const float4 v_ = *reinterpret_cast<const float4*>(&(comb)[((RR) * 16 + (CC)) * 4]); \
    const float pmx = v_.x;  const int pgx = __float_as_int(v_.y);           \
    const float pmn = v_.z;  const int pgn = __float_as_int(v_.w);           \
    if (pmx > vmax##S) { vmax##S = pmx; gx##S = pgx; }                       \
    else if (pmx == vmax##S && pgx < gx##S) { gx##S = pgx; }                 \
    if (pmn < vmin##S) { vmin##S = pmn; gn##S = pgn; }                       \
    else if (pmn == vmin##S && pgn < gn##S) { gn##S = pgn; }                 \
  }

#define MERGE_PART(comb)                                                     \
  {                                                                          \
    MERGE_ONE(00, r0, c0, comb) MERGE_ONE(01, r0, c1, comb)                  \
    MERGE_ONE(10, r1, c0, comb) MERGE_ONE(11, r1, c1, comb)                  \
  }

  if (quarter == 1) WRITE_PART(combA);
  if (quarter == 3) WRITE_PART(combB);
  __syncthreads();
  if (quarter == 0) MERGE_PART(combA);
  if (quarter == 2) MERGE_PART(combB);
  __syncthreads();
  if (quarter == 2) WRITE_PART(combA);
  __syncthreads();
  if (quarter == 0) { MERGE_PART(combA); WRITE_PART(combA); }
  __syncthreads();

  // ---- distributed output + windowed index recovery: 1 cell per thread ----
  {
    const int cell = th;                      // 0..255 = 16 rows x 16 cols
    const float4 v = *reinterpret_cast<const float4*>(&combA[cell * 4]);
    const float vmx = v.x;  const int gxc = __float_as_int(v.y);
    const float vmn = v.z;  const int gnc = __float_as_int(v.w);
    const int row = cell >> 4, col = cell & 15;
    const int n = n0 + row, m = m0 + col;
    const float* xr = &X[n * KTOT];
    const float* wr = &W[m * KTOT];
    const int imax = find_first_eq(xr + gxc, wr + gxc, vmx, gxc);
    const int imin = find_first_eq(xr + gnc, wr + gnc, vmn, gnc);

    float* Cout = out;
    float* AM   = out + NTOT * MTOT;
    float* AN   = AM + NTOT * MTOT;
    const int o = n * MTOT + m;
    Cout[o] = vmx + vmn + B[m];
    AM[o]   = (float)imax;
    AN[o]   = (float)imin;
  }
}

extern "C" void kernel_launch(void* const* d_in, const int* in_sizes, int n_in,
                              void* d_out, int out_size, void* d_ws, size_t ws_size,
                              hipStream_t stream) {
  const float* X = (const float*)d_in[0];   // [8,128,512] -> [1024][512]
  const float* W = (const float*)d_in[1];   // [512][512]
  const float* B = (const float*)d_in[2];   // [512]
  float* out = (float*)d_out;

  dim3 grid(MTOT / BM, NTOT / BN);          // (32, 64) = 2048 blocks, 256 thr
  mam_kernel<<<grid, dim3(256), 0, stream>>>(X, W, B, out);
}